// Round 1
// baseline (3013.394 us; speedup 1.0000x reference)
//
#include <hip/hip_runtime.h>

// MyTransformerEncoderLayer: B=128,S=77,D=1024,H=16,DH=64,F=4096,E=8,topK=2
// Tokens NTOK = 9856 = 77*128 (exactly 77 M-tiles of 128).
//
// Pipeline (all on `stream`, graph-capture safe):
//  1. LN1(src) -> xn (bf16)
//  2. QKV GEMM (BT weights)            xn @ packed_w^T + b -> qkv (bf16)
//  3. attention per (b,h)              -> ao (bf16)
//  4. outproj GEMM + bias + src resid  -> d_out = x (fp32)
//  5. LN2(x) -> ffn (bf16);  router on x token-0 (fp32 exact) -> top_i/gates
//  6. MoE pass k=0,1: G1 relu(ffn@ew1[e]+eb1[e]) -> h (bf16);
//                     G2 d_out += gate * (h@ew2[e]+eb2[e])
//  7. shared: G1 relu(ffn@sw1+sb1) -> h; G2 d_out += h@sw2+sb2
//
// ws layout (bytes):          [0, 20185088)  xn / ffn (aliased, lifetime disjoint)
//  [20185088, 100925440)  qkv(60555264)+ao(20185088); h (80740352) aliases both
//  [100925440, +1024) top_i ; [+1024, +2048) gates       total ~100.93 MB

typedef float f32x4 __attribute__((ext_vector_type(4)));
typedef __bf16 bf16x8 __attribute__((ext_vector_type(8)));
typedef __bf16 bf16x4 __attribute__((ext_vector_type(4)));

#define NTOK 9856
#define DMODEL 1024
#define SEQ 77

// ---------------------------------------------------------------- LayerNorm
__global__ __launch_bounds__(256)
void ln_kernel(const float* __restrict__ x, const float* __restrict__ w,
               const float* __restrict__ bb, __bf16* __restrict__ out)
{
    const int t = blockIdx.x, tid = threadIdx.x;
    const float4 v = ((const float4*)(x + (size_t)t * DMODEL))[tid];
    float s = v.x + v.y + v.z + v.w;
    float q = v.x*v.x + v.y*v.y + v.z*v.z + v.w*v.w;
#pragma unroll
    for (int off = 32; off; off >>= 1) {
        s += __shfl_xor(s, off, 64);
        q += __shfl_xor(q, off, 64);
    }
    __shared__ float rs[4], rq[4];
    const int wv = tid >> 6, lane = tid & 63;
    if (lane == 0) { rs[wv] = s; rq[wv] = q; }
    __syncthreads();
    s = rs[0] + rs[1] + rs[2] + rs[3];
    q = rq[0] + rq[1] + rq[2] + rq[3];
    const float mean = s * (1.f / 1024.f);
    const float rstd = rsqrtf(q * (1.f / 1024.f) - mean * mean + 1e-5f);
    const float4 wv4 = ((const float4*)w)[tid];
    const float4 bv4 = ((const float4*)bb)[tid];
    bf16x4 o;
    o[0] = (__bf16)((v.x - mean) * rstd * wv4.x + bv4.x);
    o[1] = (__bf16)((v.y - mean) * rstd * wv4.y + bv4.y);
    o[2] = (__bf16)((v.z - mean) * rstd * wv4.z + bv4.z);
    o[3] = (__bf16)((v.w - mean) * rstd * wv4.w + bv4.w);
    ((bf16x4*)out)[(size_t)t * 256 + tid] = o;
}

// ---------------------------------------------------------------- Router
// Recomputes LN2 of token 0 in fp32 (exact) so top-k selection can't flip.
__global__ __launch_bounds__(256)
void router_kernel(const float* __restrict__ x, const float* __restrict__ w,
                   const float* __restrict__ bb, const float* __restrict__ rw,
                   int* __restrict__ top_i, float* __restrict__ gates)
{
    const int b = blockIdx.x, tid = threadIdx.x;
    __shared__ float lnv[1024];
    __shared__ float red[8];
    __shared__ float pl[8][33];
    const float4 v = ((const float4*)(x + (size_t)b * SEQ * DMODEL))[tid];
    float s = v.x + v.y + v.z + v.w;
    float q = v.x*v.x + v.y*v.y + v.z*v.z + v.w*v.w;
#pragma unroll
    for (int off = 32; off; off >>= 1) {
        s += __shfl_xor(s, off, 64);
        q += __shfl_xor(q, off, 64);
    }
    const int wv = tid >> 6, lane = tid & 63;
    if (lane == 0) { red[wv] = s; red[4 + wv] = q; }
    __syncthreads();
    s = red[0] + red[1] + red[2] + red[3];
    q = red[4] + red[5] + red[6] + red[7];
    const float mean = s * (1.f / 1024.f);
    const float rstd = rsqrtf(q * (1.f / 1024.f) - mean * mean + 1e-5f);
    const float4 wv4 = ((const float4*)w)[tid];
    const float4 bv4 = ((const float4*)bb)[tid];
    lnv[4 * tid + 0] = (v.x - mean) * rstd * wv4.x + bv4.x;
    lnv[4 * tid + 1] = (v.y - mean) * rstd * wv4.y + bv4.y;
    lnv[4 * tid + 2] = (v.z - mean) * rstd * wv4.z + bv4.z;
    lnv[4 * tid + 3] = (v.w - mean) * rstd * wv4.w + bv4.w;
    __syncthreads();
    const int e = tid >> 5, g = tid & 31;
    float p = 0.f;
    for (int d = g; d < 1024; d += 32) p += lnv[d] * rw[(size_t)e * 1024 + d];
    pl[e][g] = p;
    __syncthreads();
    if (tid < 8) {
        float lg = 0.f;
        for (int i = 0; i < 32; ++i) lg += pl[tid][i];
        red[tid] = lg;
    }
    __syncthreads();
    if (tid == 0) {
        int i0 = 0; float v0 = red[0];
        for (int k = 1; k < 8; ++k) if (red[k] > v0) { v0 = red[k]; i0 = k; }
        int i1 = -1; float v1 = -3.4e38f;
        for (int k = 0; k < 8; ++k) if (k != i0 && red[k] > v1) { v1 = red[k]; i1 = k; }
        const float g1 = __expf(v1 - v0);
        const float invs = 1.f / (1.f + g1);
        top_i[b * 2] = i0; top_i[b * 2 + 1] = i1;
        gates[b * 2] = invs; gates[b * 2 + 1] = g1 * invs;
    }
}

// ---------------------------------------------------------------- Attention
// One block per (h, b). K/V in LDS (fp32, +1 pad kills bank conflicts),
// 4 waves round-robin over the 77 query rows, shuffle-based softmax.
__global__ __launch_bounds__(256)
void attn_kernel(const __bf16* __restrict__ qkv, __bf16* __restrict__ ao)
{
    const int h = blockIdx.x, b = blockIdx.y;
    __shared__ float Ks[77][65];
    __shared__ float Vs[77][65];
    const int tid = threadIdx.x;
    const size_t base = (size_t)b * SEQ * 3072 + (size_t)h * 64;
    for (int idx = tid; idx < 77 * 64; idx += 256) {
        const int s = idx >> 6, d = idx & 63;
        Ks[s][d] = (float)qkv[base + (size_t)s * 3072 + 1024 + d];
        Vs[s][d] = (float)qkv[base + (size_t)s * 3072 + 2048 + d];
    }
    __syncthreads();
    const int w = tid >> 6, lane = tid & 63;
    const bool has2 = (lane + 64) < 77;
    for (int s = w; s < 77; s += 4) {
        const float qv = (float)qkv[base + (size_t)s * 3072 + lane];
        float s0 = 0.f, s1 = 0.f;
        for (int d = 0; d < 64; ++d) {
            const float qd = __shfl(qv, d, 64);
            s0 += qd * Ks[lane][d];
            if (has2) s1 += qd * Ks[lane + 64][d];
        }
        s0 *= 0.125f; s1 *= 0.125f;
        float mx = has2 ? fmaxf(s0, s1) : s0;
#pragma unroll
        for (int off = 32; off; off >>= 1) mx = fmaxf(mx, __shfl_xor(mx, off, 64));
        const float p0 = __expf(s0 - mx);
        const float p1 = has2 ? __expf(s1 - mx) : 0.f;
        float sum = p0 + p1;
#pragma unroll
        for (int off = 32; off; off >>= 1) sum += __shfl_xor(sum, off, 64);
        const float inv = 1.f / sum;
        float o = 0.f;
        for (int j = 0; j < 64; ++j) o += __shfl(p0, j, 64) * Vs[j][lane];
        for (int j = 64; j < 77; ++j) o += __shfl(p1, j - 64, 64) * Vs[j][lane];
        ao[((size_t)b * SEQ + s) * DMODEL + (size_t)h * 64 + lane] = (__bf16)(o * inv);
    }
}

// ---------------------------------------------------------------- GEMM
// C[m,n] = epi( sum_k A[m,k]*W[.,.] + bias[n] ),  A bf16 [M,K] row-major.
// BLAYOUT 0: W fp32 [N,K] (BT, contiguous-K).  1: W fp32 [K,N] (BN) ->
//            transposed into LDS via scalar scatter (round-1 simplicity).
// EPI 0: bias -> bf16   1: bias+relu -> bf16
//     2: bias + resid -> fp32   3: fp32 out += gate*(acc+bias)
// MOE: blockIdx.y = batch b, 77 valid rows, weight/bias/gate selected by
//      on-device routing arrays (static grid, capture-safe).
template<int BLAYOUT, int EPI, bool MOE>
__global__ __launch_bounds__(256)
void gemm_k(const __bf16* __restrict__ A, const float* __restrict__ Bw,
            const float* __restrict__ bias, const float* __restrict__ resid,
            void* __restrict__ C, int N, int Kdim,
            const int* __restrict__ top_i, const float* __restrict__ gatesp,
            int pass, size_t bw_estride, int bias_estride)
{
    __shared__ __align__(16) __bf16 As[128][40];   // +8 pad: b128-friendly, spreads banks
    __shared__ __align__(16) __bf16 Bs[128][40];   // Bs[n][k] (B^T layout)

    const int tid = threadIdx.x;
    int row0, valid;
    float gate = 1.0f;
    if constexpr (MOE) {
        const int b = blockIdx.y;
        row0 = b * SEQ; valid = SEQ;
        const int e = top_i[b * 2 + pass];
        Bw += (size_t)e * bw_estride;
        bias += (size_t)e * (size_t)bias_estride;
        gate = gatesp[b * 2 + pass];
    } else {
        row0 = blockIdx.y * 128; valid = 128;
    }
    const int n0 = blockIdx.x * 128;

    const int ar = tid >> 1, ac = (tid & 1) << 4;      // A stage: 2 thr/row, 16 elem each
    const int bk = tid & 31, bg = tid >> 5;            // BN stage indices

    const int wave = tid >> 6, lane = tid & 63;
    const int wm = (wave >> 1) << 6, wn = (wave & 1) << 6;
    const int fr = lane & 15, fq = lane >> 4;

    f32x4 acc[4][4];
#pragma unroll
    for (int i = 0; i < 4; ++i)
#pragma unroll
        for (int j = 0; j < 4; ++j) acc[i][j] = f32x4{0.f, 0.f, 0.f, 0.f};

    const bool a_ok = (!MOE) || (ar < valid);
    const __bf16* aptr = A + (size_t)(row0 + ar) * Kdim + ac;

    for (int k0 = 0; k0 < Kdim; k0 += 32) {
        uint4 a0 = {0, 0, 0, 0}, a1 = {0, 0, 0, 0};
        if (a_ok) {
            const uint4* ap = (const uint4*)(aptr + k0);
            a0 = ap[0]; a1 = ap[1];
        }
        float4 f0, f1, f2, f3;
        if constexpr (BLAYOUT == 0) {
            const float4* bp = (const float4*)(Bw + (size_t)(n0 + ar) * Kdim + k0 + ac);
            f0 = bp[0]; f1 = bp[1]; f2 = bp[2]; f3 = bp[3];
        } else {
            const float4* bp = (const float4*)(Bw + (size_t)(k0 + bk) * N + n0 + (bg << 4));
            f0 = bp[0]; f1 = bp[1]; f2 = bp[2]; f3 = bp[3];
        }
        __syncthreads();   // prior iter's LDS reads done before overwrite
        *(uint4*)&As[ar][ac] = a0;
        *(uint4*)&As[ar][ac + 8] = a1;
        if constexpr (BLAYOUT == 0) {
            bf16x8 h0, h1;
            h0[0]=(__bf16)f0.x; h0[1]=(__bf16)f0.y; h0[2]=(__bf16)f0.z; h0[3]=(__bf16)f0.w;
            h0[4]=(__bf16)f1.x; h0[5]=(__bf16)f1.y; h0[6]=(__bf16)f1.z; h0[7]=(__bf16)f1.w;
            h1[0]=(__bf16)f2.x; h1[1]=(__bf16)f2.y; h1[2]=(__bf16)f2.z; h1[3]=(__bf16)f2.w;
            h1[4]=(__bf16)f3.x; h1[5]=(__bf16)f3.y; h1[6]=(__bf16)f3.z; h1[7]=(__bf16)f3.w;
            *(bf16x8*)&Bs[ar][ac] = h0;
            *(bf16x8*)&Bs[ar][ac + 8] = h1;
        } else {
            const int nb = bg << 4;
            Bs[nb + 0][bk] = (__bf16)f0.x;  Bs[nb + 1][bk] = (__bf16)f0.y;
            Bs[nb + 2][bk] = (__bf16)f0.z;  Bs[nb + 3][bk] = (__bf16)f0.w;
            Bs[nb + 4][bk] = (__bf16)f1.x;  Bs[nb + 5][bk] = (__bf16)f1.y;
            Bs[nb + 6][bk] = (__bf16)f1.z;  Bs[nb + 7][bk] = (__bf16)f1.w;
            Bs[nb + 8][bk] = (__bf16)f2.x;  Bs[nb + 9][bk] = (__bf16)f2.y;
            Bs[nb + 10][bk] = (__bf16)f2.z; Bs[nb + 11][bk] = (__bf16)f2.w;
            Bs[nb + 12][bk] = (__bf16)f3.x; Bs[nb + 13][bk] = (__bf16)f3.y;
            Bs[nb + 14][bk] = (__bf16)f3.z; Bs[nb + 15][bk] = (__bf16)f3.w;
        }
        __syncthreads();
        bf16x8 af[4], bfr[4];
#pragma unroll
        for (int mm = 0; mm < 4; ++mm)
            af[mm] = *(const bf16x8*)&As[wm + mm * 16 + fr][fq << 3];
#pragma unroll
        for (int nn = 0; nn < 4; ++nn)
            bfr[nn] = *(const bf16x8*)&Bs[wn + nn * 16 + fr][fq << 3];
#pragma unroll
        for (int mm = 0; mm < 4; ++mm)
#pragma unroll
            for (int nn = 0; nn < 4; ++nn)
                acc[mm][nn] = __builtin_amdgcn_mfma_f32_16x16x32_bf16(
                    af[mm], bfr[nn], acc[mm][nn], 0, 0, 0);
    }

    float bv[4];
#pragma unroll
    for (int nn = 0; nn < 4; ++nn) bv[nn] = bias[n0 + wn + nn * 16 + fr];
#pragma unroll
    for (int mm = 0; mm < 4; ++mm) {
#pragma unroll
        for (int r = 0; r < 4; ++r) {
            const int m = wm + mm * 16 + (fq << 2) + r;   // C/D: row=quad*4+reg
            if (!MOE || m < valid) {
                const size_t rowb = (size_t)(row0 + m) * N;
#pragma unroll
                for (int nn = 0; nn < 4; ++nn) {
                    const int n = n0 + wn + nn * 16 + fr; // C/D: col=lane&15
                    float v = acc[mm][nn][r] + bv[nn];
                    if constexpr (EPI == 0) {
                        ((__bf16*)C)[rowb + n] = (__bf16)v;
                    } else if constexpr (EPI == 1) {
                        ((__bf16*)C)[rowb + n] = (__bf16)fmaxf(v, 0.f);
                    } else if constexpr (EPI == 2) {
                        ((float*)C)[rowb + n] = v + resid[rowb + n];
                    } else {
                        ((float*)C)[rowb + n] += gate * v;
                    }
                }
            }
        }
    }
}

// ---------------------------------------------------------------- launch
extern "C" void kernel_launch(void* const* d_in, const int* in_sizes, int n_in,
                              void* d_out, int out_size, void* d_ws, size_t ws_size,
                              hipStream_t stream)
{
    (void)in_sizes; (void)n_in; (void)out_size; (void)ws_size;
    const float* src      = (const float*)d_in[0];
    const float* packed_w = (const float*)d_in[1];
    const float* packed_b = (const float*)d_in[2];
    const float* out_w    = (const float*)d_in[3];
    const float* out_b    = (const float*)d_in[4];
    const float* ln1_w    = (const float*)d_in[5];
    const float* ln1_b    = (const float*)d_in[6];
    const float* ln2_w    = (const float*)d_in[7];
    const float* ln2_b    = (const float*)d_in[8];
    const float* router_w = (const float*)d_in[9];
    const float* ew1      = (const float*)d_in[10];
    const float* eb1      = (const float*)d_in[11];
    const float* ew2      = (const float*)d_in[12];
    const float* eb2      = (const float*)d_in[13];
    const float* sw1      = (const float*)d_in[14];
    const float* sb1      = (const float*)d_in[15];
    const float* sw2      = (const float*)d_in[16];
    const float* sb2      = (const float*)d_in[17];
    float* out = (float*)d_out;

    char* ws = (char*)d_ws;
    __bf16* xn   = (__bf16*)(ws);                  // 20,185,088 B
    __bf16* qkv  = (__bf16*)(ws + 20185088);       // 60,555,264 B
    __bf16* ao   = (__bf16*)(ws + 80740352);       // 20,185,088 B
    __bf16* hws  = (__bf16*)(ws + 20185088);       // aliases qkv+ao (lifetimes disjoint)
    __bf16* ffn  = xn;                             // aliases xn
    int*    top_i = (int*)(ws + 100925440);
    float*  gates = (float*)(ws + 100925440 + 1024);

    // 1. LN1
    ln_kernel<<<NTOK, 256, 0, stream>>>(src, ln1_w, ln1_b, xn);
    // 2. QKV projection  [9856,1024]x[3072,1024]^T
    gemm_k<0, 0, false><<<dim3(24, 77), 256, 0, stream>>>(
        xn, packed_w, packed_b, nullptr, qkv, 3072, 1024,
        nullptr, nullptr, 0, 0, 0);
    // 3. attention
    attn_kernel<<<dim3(16, 128), 256, 0, stream>>>(qkv, ao);
    // 4. out projection + bias + residual -> x (fp32) in d_out
    gemm_k<0, 2, false><<<dim3(8, 77), 256, 0, stream>>>(
        ao, out_w, out_b, src, out, 1024, 1024,
        nullptr, nullptr, 0, 0, 0);
    // 5. LN2 + router (router reads x fp32, recomputes LN exactly)
    ln_kernel<<<NTOK, 256, 0, stream>>>(out, ln2_w, ln2_b, ffn);
    router_kernel<<<128, 256, 0, stream>>>(out, ln2_w, ln2_b, router_w, top_i, gates);
    // 6. MoE expert passes (k = 0, 1), h reuses qkv+ao region
    for (int pass = 0; pass < 2; ++pass) {
        gemm_k<1, 1, true><<<dim3(32, 128), 256, 0, stream>>>(
            ffn, ew1, eb1, nullptr, hws, 4096, 1024,
            top_i, gates, pass, (size_t)1024 * 4096, 4096);
        gemm_k<1, 3, true><<<dim3(8, 128), 256, 0, stream>>>(
            hws, ew2, eb2, nullptr, out, 1024, 4096,
            top_i, gates, pass, (size_t)4096 * 1024, 1024);
    }
    // 7. shared expert (gate = 1 accumulate)
    gemm_k<1, 1, false><<<dim3(32, 77), 256, 0, stream>>>(
        ffn, sw1, sb1, nullptr, hws, 4096, 1024,
        nullptr, nullptr, 0, 0, 0);
    gemm_k<1, 3, false><<<dim3(8, 77), 256, 0, stream>>>(
        hws, sw2, sb2, nullptr, out, 1024, 4096,
        nullptr, nullptr, 0, 0, 0);
}

// Round 2
// 1847.638 us; speedup vs baseline: 1.6309x; 1.6309x over previous
//
#include <hip/hip_runtime.h>

// MyTransformerEncoderLayer: B=128,S=77,D=1024,H=16,DH=64,F=4096,E=8,topK=2
// Round 2: MFMA attention + m97-style bf16 BT GEMMs with pre-converted weights.
//
// New-path ws layout (bytes), FULL_NEED = 261,621,760 (~249.5 MiB):
//   [0,          75497472)   w1T  bf16 [9][4096][1024]   (ew1 + sw1, transposed)
//   [75497472,  150994944)   w2T  bf16 [9][1024][4096]   (ew2 + sw2, transposed)
//   [150994944, 157286400)   packed_w bf16 [3072][1024]
//   [157286400, 159383552)   out_w    bf16 [1024][1024]
//   [159383552, 179830784)   xn/ffn bf16, padded to 9984 rows
//   [179830784, 261619712)   big: qkv(60555264)+ao(20185088); h(81788928) aliases
//   [261619712, 261621760)   top_i + gates
// Fallback (ws_size < FULL_NEED): round-1 pipeline (fp32 weights, guarded
// uint4 staging GEMM) with the new MFMA attention.

typedef float f32x4 __attribute__((ext_vector_type(4)));
typedef __bf16 bf16x8 __attribute__((ext_vector_type(8)));
typedef __bf16 bf16x4 __attribute__((ext_vector_type(4)));

#define NTOK 9856
#define DMODEL 1024
#define SEQ 77

__device__ __forceinline__ void gl16(const __bf16* g, __bf16* l) {
    __builtin_amdgcn_global_load_lds(
        (const __attribute__((address_space(1))) unsigned int*)g,
        (__attribute__((address_space(3))) unsigned int*)l, 16, 0, 0);
}

// ---------------------------------------------------------------- LayerNorm
__global__ __launch_bounds__(256)
void ln_kernel(const float* __restrict__ x, const float* __restrict__ w,
               const float* __restrict__ bb, __bf16* __restrict__ out)
{
    const int t = blockIdx.x, tid = threadIdx.x;
    const float4 v = ((const float4*)(x + (size_t)t * DMODEL))[tid];
    float s = v.x + v.y + v.z + v.w;
    float q = v.x*v.x + v.y*v.y + v.z*v.z + v.w*v.w;
#pragma unroll
    for (int off = 32; off; off >>= 1) {
        s += __shfl_xor(s, off, 64);
        q += __shfl_xor(q, off, 64);
    }
    __shared__ float rs[4], rq[4];
    const int wv = tid >> 6, lane = tid & 63;
    if (lane == 0) { rs[wv] = s; rq[wv] = q; }
    __syncthreads();
    s = rs[0] + rs[1] + rs[2] + rs[3];
    q = rq[0] + rq[1] + rq[2] + rq[3];
    const float mean = s * (1.f / 1024.f);
    const float rstd = rsqrtf(q * (1.f / 1024.f) - mean * mean + 1e-5f);
    const float4 wv4 = ((const float4*)w)[tid];
    const float4 bv4 = ((const float4*)bb)[tid];
    bf16x4 o;
    o[0] = (__bf16)((v.x - mean) * rstd * wv4.x + bv4.x);
    o[1] = (__bf16)((v.y - mean) * rstd * wv4.y + bv4.y);
    o[2] = (__bf16)((v.z - mean) * rstd * wv4.z + bv4.z);
    o[3] = (__bf16)((v.w - mean) * rstd * wv4.w + bv4.w);
    ((bf16x4*)out)[(size_t)t * 256 + tid] = o;
}

// ---------------------------------------------------------------- Router
__global__ __launch_bounds__(256)
void router_kernel(const float* __restrict__ x, const float* __restrict__ w,
                   const float* __restrict__ bb, const float* __restrict__ rw,
                   int* __restrict__ top_i, float* __restrict__ gates)
{
    const int b = blockIdx.x, tid = threadIdx.x;
    __shared__ float lnv[1024];
    __shared__ float red[8];
    __shared__ float pl[8][33];
    const float4 v = ((const float4*)(x + (size_t)b * SEQ * DMODEL))[tid];
    float s = v.x + v.y + v.z + v.w;
    float q = v.x*v.x + v.y*v.y + v.z*v.z + v.w*v.w;
#pragma unroll
    for (int off = 32; off; off >>= 1) {
        s += __shfl_xor(s, off, 64);
        q += __shfl_xor(q, off, 64);
    }
    const int wv = tid >> 6, lane = tid & 63;
    if (lane == 0) { red[wv] = s; red[4 + wv] = q; }
    __syncthreads();
    s = red[0] + red[1] + red[2] + red[3];
    q = red[4] + red[5] + red[6] + red[7];
    const float mean = s * (1.f / 1024.f);
    const float rstd = rsqrtf(q * (1.f / 1024.f) - mean * mean + 1e-5f);
    const float4 wv4 = ((const float4*)w)[tid];
    const float4 bv4 = ((const float4*)bb)[tid];
    lnv[4 * tid + 0] = (v.x - mean) * rstd * wv4.x + bv4.x;
    lnv[4 * tid + 1] = (v.y - mean) * rstd * wv4.y + bv4.y;
    lnv[4 * tid + 2] = (v.z - mean) * rstd * wv4.z + bv4.z;
    lnv[4 * tid + 3] = (v.w - mean) * rstd * wv4.w + bv4.w;
    __syncthreads();
    const int e = tid >> 5, g = tid & 31;
    float p = 0.f;
    for (int d = g; d < 1024; d += 32) p += lnv[d] * rw[(size_t)e * 1024 + d];
    pl[e][g] = p;
    __syncthreads();
    if (tid < 8) {
        float lg = 0.f;
        for (int i = 0; i < 32; ++i) lg += pl[tid][i];
        red[tid] = lg;
    }
    __syncthreads();
    if (tid == 0) {
        int i0 = 0; float v0 = red[0];
        for (int k = 1; k < 8; ++k) if (red[k] > v0) { v0 = red[k]; i0 = k; }
        int i1 = -1; float v1 = -3.4e38f;
        for (int k = 0; k < 8; ++k) if (k != i0 && red[k] > v1) { v1 = red[k]; i1 = k; }
        const float g1 = __expf(v1 - v0);
        const float invs = 1.f / (1.f + g1);
        top_i[b * 2] = i0; top_i[b * 2 + 1] = i1;
        gates[b * 2] = invs; gates[b * 2 + 1] = g1 * invs;
    }
}

// ---------------------------------------------------------------- MFMA attention
// One block per (h,b). S padded 77->80 (M,N), PV k padded 77->96.
// LDS pool (64,768 B): Ks[80][64] | Vt[64][96] | Ss[80][84] f32 | X(Qs/Ps)
__global__ __launch_bounds__(256)
void attn_mfma(const __bf16* __restrict__ qkv, __bf16* __restrict__ ao)
{
    const int h = blockIdx.x, b = blockIdx.y;
    const int tid = threadIdx.x;
    __shared__ __align__(16) char pool[64768];
    __bf16 (*Ks)[64] = (__bf16(*)[64])pool;                 // 10,240
    __bf16 (*Vt)[96] = (__bf16(*)[96])(pool + 10240);       // 12,288
    float  (*Ss)[84] = (float (*)[84])(pool + 22528);       // 26,880
    __bf16 (*Qs)[64] = (__bf16(*)[64])(pool + 49408);       // 10,240 (aliases Ps)
    __bf16 (*Ps)[96] = (__bf16(*)[96])(pool + 49408);       // 15,360

    const size_t base = (size_t)b * SEQ * 3072 + (size_t)h * 64;

    // ---- load Q,K (8-elem vector chunks), V transposed, zero pads ----
    for (int c = tid; c < 77 * 8; c += 256) {
        const int s = c >> 3, d0 = (c & 7) << 3;
        *(bf16x8*)&Qs[s][d0] = *(const bf16x8*)&qkv[base + (size_t)s * 3072 + d0];
        *(bf16x8*)&Ks[s][d0] = *(const bf16x8*)&qkv[base + (size_t)s * 3072 + 1024 + d0];
    }
    for (int c = tid; c < 3 * 64; c += 256) {
        const int s = 77 + (c >> 6), d = c & 63;
        Qs[s][d] = (__bf16)0.f; Ks[s][d] = (__bf16)0.f;
    }
    for (int c = tid; c < 77 * 8; c += 256) {
        const int s = c >> 3, d0 = (c & 7) << 3;
        bf16x8 v = *(const bf16x8*)&qkv[base + (size_t)s * 3072 + 2048 + d0];
#pragma unroll
        for (int j = 0; j < 8; ++j) Vt[d0 + j][s] = v[j];
    }
    for (int c = tid; c < 64 * 19; c += 256) {
        const int d = c / 19, s = 77 + c % 19;
        Vt[d][s] = (__bf16)0.f;
    }
    __syncthreads();

    const int wv = tid >> 6, ln = tid & 63;
    const int fr = ln & 15, fq = ln >> 4;

    // ---- S = (Q K^T) * 0.125 : 25 fragment tiles round-robin over waves ----
    for (int f = wv; f < 25; f += 4) {
        const int mt = f / 5, nt = f - mt * 5;
        bf16x8 a0 = *(const bf16x8*)&Qs[mt * 16 + fr][fq * 8];
        bf16x8 a1 = *(const bf16x8*)&Qs[mt * 16 + fr][32 + fq * 8];
        bf16x8 b0 = *(const bf16x8*)&Ks[nt * 16 + fr][fq * 8];
        bf16x8 b1 = *(const bf16x8*)&Ks[nt * 16 + fr][32 + fq * 8];
        f32x4 acc = {0.f, 0.f, 0.f, 0.f};
        acc = __builtin_amdgcn_mfma_f32_16x16x32_bf16(a0, b0, acc, 0, 0, 0);
        acc = __builtin_amdgcn_mfma_f32_16x16x32_bf16(a1, b1, acc, 0, 0, 0);
#pragma unroll
        for (int r = 0; r < 4; ++r)
            Ss[mt * 16 + fq * 4 + r][nt * 16 + fr] = acc[r] * 0.125f;
    }
    __syncthreads();   // Qs dead from here; Ps may overwrite it

    // ---- softmax rows (cols 0..76 valid), P -> bf16 A-layout ----
    if (tid < 80) {
        float mx = -1e30f;
        for (int c = 0; c < 77; ++c) mx = fmaxf(mx, Ss[tid][c]);
        float sum = 0.f;
        for (int c = 0; c < 77; ++c) {
            const float e2 = __expf(Ss[tid][c] - mx);
            Ss[tid][c] = e2; sum += e2;
        }
        const float inv = 1.f / sum;
        for (int c = 0; c < 77; ++c) Ps[tid][c] = (__bf16)(Ss[tid][c] * inv);
        for (int c = 77; c < 96; ++c) Ps[tid][c] = (__bf16)0.f;
    }
    __syncthreads();

    // ---- O = P V : 20 fragment tiles, k = 96 (3 chunks) ----
    for (int f = wv; f < 20; f += 4) {
        const int mt = f >> 2, nt = f & 3;
        f32x4 acc = {0.f, 0.f, 0.f, 0.f};
#pragma unroll
        for (int kk = 0; kk < 3; ++kk) {
            bf16x8 a = *(const bf16x8*)&Ps[mt * 16 + fr][kk * 32 + fq * 8];
            bf16x8 bb = *(const bf16x8*)&Vt[nt * 16 + fr][kk * 32 + fq * 8];
            acc = __builtin_amdgcn_mfma_f32_16x16x32_bf16(a, bb, acc, 0, 0, 0);
        }
#pragma unroll
        for (int r = 0; r < 4; ++r) {
            const int m = mt * 16 + fq * 4 + r;
            if (m < 77)
                ao[((size_t)b * SEQ + m) * DMODEL + (size_t)h * 64 + nt * 16 + fr]
                    = (__bf16)acc[r];
        }
    }
}

// ---------------------------------------------------------------- weight prep
__global__ __launch_bounds__(256)
void cvt_kernel(const float* __restrict__ in, __bf16* __restrict__ out, int n4)
{
    const int i = blockIdx.x * 256 + threadIdx.x;
    if (i < n4) {
        const float4 v = ((const float4*)in)[i];
        bf16x4 o;
        o[0] = (__bf16)v.x; o[1] = (__bf16)v.y; o[2] = (__bf16)v.z; o[3] = (__bf16)v.w;
        ((bf16x4*)out)[i] = o;
    }
}

// in fp32 [R][C] (z<8: e_in + z*R*C, z==8: s_in) -> out bf16 [C][R]
__global__ __launch_bounds__(256)
void transpose_cvt(const float* __restrict__ e_in, const float* __restrict__ s_in,
                   __bf16* __restrict__ outw, int R, int C)
{
    const int z = blockIdx.z;
    const float* in = (z == 8) ? s_in : e_in + (size_t)z * R * C;
    __bf16* out = outw + (size_t)z * R * C;
    __shared__ float t[32][33];
    const int tr = threadIdx.x >> 3, tc4 = (threadIdx.x & 7) << 2;
    const int r0 = blockIdx.y << 5, c0 = blockIdx.x << 5;
    const float4 v = *(const float4*)&in[(size_t)(r0 + tr) * C + c0 + tc4];
    t[tr][tc4 + 0] = v.x; t[tr][tc4 + 1] = v.y;
    t[tr][tc4 + 2] = v.z; t[tr][tc4 + 3] = v.w;
    __syncthreads();
    bf16x4 o;
    o[0] = (__bf16)t[tc4 + 0][tr]; o[1] = (__bf16)t[tc4 + 1][tr];
    o[2] = (__bf16)t[tc4 + 2][tr]; o[3] = (__bf16)t[tc4 + 3][tr];
    *(bf16x4*)&out[(size_t)(c0 + tr) * R + r0 + tc4] = o;
}

// ---------------------------------------------------------------- GEMM (bf16 BT)
// m97 structure: 128x128 tile, BK=64, global_load_lds width-16 staging.
// A [M,K] bf16 row-major (padded rows for MOE tiles), Bw [N,K] bf16.
// EPI 0: bias->bf16  1: bias+relu->bf16  2: bias+resid->fp32  3: fp32 += gate*(..)
template<int EPI, bool MOE>
__global__ __launch_bounds__(256)
void gemm_bt(const __bf16* __restrict__ A, const __bf16* __restrict__ Bw,
             const float* __restrict__ bias, const float* __restrict__ resid,
             void* __restrict__ C, int N, int Kdim,
             const int* __restrict__ top_i, const float* __restrict__ gatesp,
             int pass, size_t bw_estride, int bias_estride)
{
    __shared__ __align__(16) __bf16 As[128][64];
    __shared__ __align__(16) __bf16 Bs[128][64];
    const int tid = threadIdx.x;
    int row0, valid;
    float gate = 1.f;
    if constexpr (MOE) {
        const int b = blockIdx.y;
        row0 = b * SEQ; valid = SEQ;
        const int e = top_i[b * 2 + pass];
        Bw += (size_t)e * bw_estride;
        bias += (size_t)e * (size_t)bias_estride;
        gate = gatesp[b * 2 + pass];
    } else { row0 = blockIdx.y * 128; valid = 128; }
    const int n0 = blockIdx.x * 128;

    const int wv = tid >> 6, ln = tid & 63;
    const int srow = wv * 32 + (ln >> 3), scol = (ln & 7) << 3;
    const __bf16* ag = A + (size_t)(row0 + srow) * Kdim + scol;
    const __bf16* bg = Bw + (size_t)(n0 + srow) * Kdim + scol;
    __bf16* asl = &As[0][0] + wv * 2048;   // wave-uniform LDS base
    __bf16* bsl = &Bs[0][0] + wv * 2048;

    const int fr = ln & 15, fq = ln >> 4;
    const int wm = (wv >> 1) << 6, wn = (wv & 1) << 6;

    f32x4 acc[4][4];
#pragma unroll
    for (int i = 0; i < 4; ++i)
#pragma unroll
        for (int j = 0; j < 4; ++j) acc[i][j] = f32x4{0.f, 0.f, 0.f, 0.f};

    for (int k0 = 0; k0 < Kdim; k0 += 64) {
        __syncthreads();                       // prior LDS reads complete
#pragma unroll
        for (int i = 0; i < 4; ++i) {
            gl16(ag + (size_t)i * 8 * Kdim, asl + i * 512);
            gl16(bg + (size_t)i * 8 * Kdim, bsl + i * 512);
        }
        ag += 64; bg += 64;
        __syncthreads();                       // vmcnt drain + barrier
        bf16x8 af[2][4], bf2[2][4];
#pragma unroll
        for (int kk = 0; kk < 2; ++kk) {
#pragma unroll
            for (int mm = 0; mm < 4; ++mm)
                af[kk][mm] = *(const bf16x8*)&As[wm + mm * 16 + fr][kk * 32 + fq * 8];
#pragma unroll
            for (int nn = 0; nn < 4; ++nn)
                bf2[kk][nn] = *(const bf16x8*)&Bs[wn + nn * 16 + fr][kk * 32 + fq * 8];
        }
#pragma unroll
        for (int mm = 0; mm < 4; ++mm)
#pragma unroll
            for (int nn = 0; nn < 4; ++nn) {
                acc[mm][nn] = __builtin_amdgcn_mfma_f32_16x16x32_bf16(
                    af[0][mm], bf2[0][nn], acc[mm][nn], 0, 0, 0);
                acc[mm][nn] = __builtin_amdgcn_mfma_f32_16x16x32_bf16(
                    af[1][mm], bf2[1][nn], acc[mm][nn], 0, 0, 0);
            }
    }

    float bv[4];
#pragma unroll
    for (int nn = 0; nn < 4; ++nn) bv[nn] = bias[n0 + wn + nn * 16 + fr];
#pragma unroll
    for (int mm = 0; mm < 4; ++mm) {
#pragma unroll
        for (int r = 0; r < 4; ++r) {
            const int m = wm + mm * 16 + (fq << 2) + r;
            if (!MOE || m < valid) {
                const size_t rowb = (size_t)(row0 + m) * N;
#pragma unroll
                for (int nn = 0; nn < 4; ++nn) {
                    const int n = n0 + wn + nn * 16 + fr;
                    float v = acc[mm][nn][r] + bv[nn];
                    if constexpr (EPI == 0) {
                        ((__bf16*)C)[rowb + n] = (__bf16)v;
                    } else if constexpr (EPI == 1) {
                        ((__bf16*)C)[rowb + n] = (__bf16)fmaxf(v, 0.f);
                    } else if constexpr (EPI == 2) {
                        ((float*)C)[rowb + n] = v + resid[rowb + n];
                    } else {
                        ((float*)C)[rowb + n] += gate * v;
                    }
                }
            }
        }
    }
}

// ---------------------------------------------------------------- GEMM (round-1 fallback)
template<int BLAYOUT, int EPI, bool MOE>
__global__ __launch_bounds__(256)
void gemm_k(const __bf16* __restrict__ A, const float* __restrict__ Bw,
            const float* __restrict__ bias, const float* __restrict__ resid,
            void* __restrict__ C, int N, int Kdim,
            const int* __restrict__ top_i, const float* __restrict__ gatesp,
            int pass, size_t bw_estride, int bias_estride)
{
    __shared__ __align__(16) __bf16 As[128][40];
    __shared__ __align__(16) __bf16 Bs[128][40];
    const int tid = threadIdx.x;
    int row0, valid;
    float gate = 1.0f;
    if constexpr (MOE) {
        const int b = blockIdx.y;
        row0 = b * SEQ; valid = SEQ;
        const int e = top_i[b * 2 + pass];
        Bw += (size_t)e * bw_estride;
        bias += (size_t)e * (size_t)bias_estride;
        gate = gatesp[b * 2 + pass];
    } else { row0 = blockIdx.y * 128; valid = 128; }
    const int n0 = blockIdx.x * 128;
    const int ar = tid >> 1, ac = (tid & 1) << 4;
    const int bk = tid & 31, bg = tid >> 5;
    const int wave = tid >> 6, lane = tid & 63;
    const int wm = (wave >> 1) << 6, wn = (wave & 1) << 6;
    const int fr = lane & 15, fq = lane >> 4;
    f32x4 acc[4][4];
#pragma unroll
    for (int i = 0; i < 4; ++i)
#pragma unroll
        for (int j = 0; j < 4; ++j) acc[i][j] = f32x4{0.f, 0.f, 0.f, 0.f};
    const bool a_ok = (!MOE) || (ar < valid);
    const __bf16* aptr = A + (size_t)(row0 + ar) * Kdim + ac;
    for (int k0 = 0; k0 < Kdim; k0 += 32) {
        uint4 a0 = {0, 0, 0, 0}, a1 = {0, 0, 0, 0};
        if (a_ok) {
            const uint4* ap = (const uint4*)(aptr + k0);
            a0 = ap[0]; a1 = ap[1];
        }
        float4 f0, f1, f2, f3;
        if constexpr (BLAYOUT == 0) {
            const float4* bp = (const float4*)(Bw + (size_t)(n0 + ar) * Kdim + k0 + ac);
            f0 = bp[0]; f1 = bp[1]; f2 = bp[2]; f3 = bp[3];
        } else {
            const float4* bp = (const float4*)(Bw + (size_t)(k0 + bk) * N + n0 + (bg << 4));
            f0 = bp[0]; f1 = bp[1]; f2 = bp[2]; f3 = bp[3];
        }
        __syncthreads();
        *(uint4*)&As[ar][ac] = a0;
        *(uint4*)&As[ar][ac + 8] = a1;
        if constexpr (BLAYOUT == 0) {
            bf16x8 h0, h1;
            h0[0]=(__bf16)f0.x; h0[1]=(__bf16)f0.y; h0[2]=(__bf16)f0.z; h0[3]=(__bf16)f0.w;
            h0[4]=(__bf16)f1.x; h0[5]=(__bf16)f1.y; h0[6]=(__bf16)f1.z; h0[7]=(__bf16)f1.w;
            h1[0]=(__bf16)f2.x; h1[1]=(__bf16)f2.y; h1[2]=(__bf16)f2.z; h1[3]=(__bf16)f2.w;
            h1[4]=(__bf16)f3.x; h1[5]=(__bf16)f3.y; h1[6]=(__bf16)f3.z; h1[7]=(__bf16)f3.w;
            *(bf16x8*)&Bs[ar][ac] = h0;
            *(bf16x8*)&Bs[ar][ac + 8] = h1;
        } else {
            const int nb = bg << 4;
            Bs[nb + 0][bk] = (__bf16)f0.x;  Bs[nb + 1][bk] = (__bf16)f0.y;
            Bs[nb + 2][bk] = (__bf16)f0.z;  Bs[nb + 3][bk] = (__bf16)f0.w;
            Bs[nb + 4][bk] = (__bf16)f1.x;  Bs[nb + 5][bk] = (__bf16)f1.y;
            Bs[nb + 6][bk] = (__bf16)f1.z;  Bs[nb + 7][bk] = (__bf16)f1.w;
            Bs[nb + 8][bk] = (__bf16)f2.x;  Bs[nb + 9][bk] = (__bf16)f2.y;
            Bs[nb + 10][bk] = (__bf16)f2.z; Bs[nb + 11][bk] = (__bf16)f2.w;
            Bs[nb + 12][bk] = (__bf16)f3.x; Bs[nb + 13][bk] = (__bf16)f3.y;
            Bs[nb + 14][bk] = (__bf16)f3.z; Bs[nb + 15][bk] = (__bf16)f3.w;
        }
        __syncthreads();
        bf16x8 af[4], bfr[4];
#pragma unroll
        for (int mm = 0; mm < 4; ++mm)
            af[mm] = *(const bf16x8*)&As[wm + mm * 16 + fr][fq << 3];
#pragma unroll
        for (int nn = 0; nn < 4; ++nn)
            bfr[nn] = *(const bf16x8*)&Bs[wn + nn * 16 + fr][fq << 3];
#pragma unroll
        for (int mm = 0; mm < 4; ++mm)
#pragma unroll
            for (int nn = 0; nn < 4; ++nn)
                acc[mm][nn] = __builtin_amdgcn_mfma_f32_16x16x32_bf16(
                    af[mm], bfr[nn], acc[mm][nn], 0, 0, 0);
    }
    float bv[4];
#pragma unroll
    for (int nn = 0; nn < 4; ++nn) bv[nn] = bias[n0 + wn + nn * 16 + fr];
#pragma unroll
    for (int mm = 0; mm < 4; ++mm) {
#pragma unroll
        for (int r = 0; r < 4; ++r) {
            const int m = wm + mm * 16 + (fq << 2) + r;
            if (!MOE || m < valid) {
                const size_t rowb = (size_t)(row0 + m) * N;
#pragma unroll
                for (int nn = 0; nn < 4; ++nn) {
                    const int n = n0 + wn + nn * 16 + fr;
                    float v = acc[mm][nn][r] + bv[nn];
                    if constexpr (EPI == 0) {
                        ((__bf16*)C)[rowb + n] = (__bf16)v;
                    } else if constexpr (EPI == 1) {
                        ((__bf16*)C)[rowb + n] = (__bf16)fmaxf(v, 0.f);
                    } else if constexpr (EPI == 2) {
                        ((float*)C)[rowb + n] = v + resid[rowb + n];
                    } else {
                        ((float*)C)[rowb + n] += gate * v;
                    }
                }
            }
        }
    }
}

// ---------------------------------------------------------------- launch
extern "C" void kernel_launch(void* const* d_in, const int* in_sizes, int n_in,
                              void* d_out, int out_size, void* d_ws, size_t ws_size,
                              hipStream_t stream)
{
    (void)in_sizes; (void)n_in; (void)out_size;
    const float* src      = (const float*)d_in[0];
    const float* packed_w = (const float*)d_in[1];
    const float* packed_b = (const float*)d_in[2];
    const float* out_w    = (const float*)d_in[3];
    const float* out_b    = (const float*)d_in[4];
    const float* ln1_w    = (const float*)d_in[5];
    const float* ln1_b    = (const float*)d_in[6];
    const float* ln2_w    = (const float*)d_in[7];
    const float* ln2_b    = (const float*)d_in[8];
    const float* router_w = (const float*)d_in[9];
    const float* ew1      = (const float*)d_in[10];
    const float* eb1      = (const float*)d_in[11];
    const float* ew2      = (const float*)d_in[12];
    const float* eb2      = (const float*)d_in[13];
    const float* sw1      = (const float*)d_in[14];
    const float* sb1      = (const float*)d_in[15];
    const float* sw2      = (const float*)d_in[16];
    const float* sb2      = (const float*)d_in[17];
    float* out = (float*)d_out;
    char* ws = (char*)d_ws;

    const size_t FULL_NEED = 261621760;
    if (ws_size >= FULL_NEED) {
        __bf16* w1T  = (__bf16*)(ws);                   // [9][4096][1024]
        __bf16* w2T  = (__bf16*)(ws + 75497472);        // [9][1024][4096]
        __bf16* pwB  = (__bf16*)(ws + 150994944);       // [3072][1024]
        __bf16* owB  = (__bf16*)(ws + 157286400);       // [1024][1024]
        __bf16* xn   = (__bf16*)(ws + 159383552);       // 9984 rows padded
        char*   big  = ws + 179830784;
        __bf16* qkv  = (__bf16*)big;
        __bf16* ao   = (__bf16*)(big + 60555264);
        __bf16* hws  = (__bf16*)big;                    // 9984 x 4096
        int*    top_i = (int*)(ws + 261619712);
        float*  gates = (float*)(ws + 261619712 + 1024);

        // weight prep
        cvt_kernel<<<3072, 256, 0, stream>>>(packed_w, pwB, 786432);
        cvt_kernel<<<1024, 256, 0, stream>>>(out_w, owB, 262144);
        transpose_cvt<<<dim3(128, 32, 9), 256, 0, stream>>>(ew1, sw1, w1T, 1024, 4096);
        transpose_cvt<<<dim3(32, 128, 9), 256, 0, stream>>>(ew2, sw2, w2T, 4096, 1024);
        // attention block
        ln_kernel<<<NTOK, 256, 0, stream>>>(src, ln1_w, ln1_b, xn);
        gemm_bt<0, false><<<dim3(24, 77), 256, 0, stream>>>(
            xn, pwB, packed_b, nullptr, qkv, 3072, 1024, nullptr, nullptr, 0, 0, 0);
        attn_mfma<<<dim3(16, 128), 256, 0, stream>>>(qkv, ao);
        gemm_bt<2, false><<<dim3(8, 77), 256, 0, stream>>>(
            ao, owB, out_b, src, out, 1024, 1024, nullptr, nullptr, 0, 0, 0);
        // MoE block
        ln_kernel<<<NTOK, 256, 0, stream>>>(out, ln2_w, ln2_b, xn);
        router_kernel<<<128, 256, 0, stream>>>(out, ln2_w, ln2_b, router_w, top_i, gates);
        for (int pass = 0; pass < 2; ++pass) {
            gemm_bt<1, true><<<dim3(32, 128), 256, 0, stream>>>(
                xn, w1T, eb1, nullptr, hws, 4096, 1024,
                top_i, gates, pass, (size_t)4194304, 4096);
            gemm_bt<3, true><<<dim3(8, 128), 256, 0, stream>>>(
                hws, w2T, eb2, nullptr, out, 1024, 4096,
                top_i, gates, pass, (size_t)4194304, 1024);
        }
        gemm_bt<1, false><<<dim3(32, 77), 256, 0, stream>>>(
            xn, w1T + (size_t)8 * 4194304, sb1, nullptr, hws, 4096, 1024,
            nullptr, nullptr, 0, 0, 0);
        gemm_bt<3, false><<<dim3(8, 77), 256, 0, stream>>>(
            hws, w2T + (size_t)8 * 4194304, sb2, nullptr, out, 1024, 4096,
            nullptr, nullptr, 0, 0, 0);
    } else {
        // -------- round-1 fallback (fp32 weights) with MFMA attention --------
        __bf16* xn   = (__bf16*)(ws);
        __bf16* qkv  = (__bf16*)(ws + 20185088);
        __bf16* ao   = (__bf16*)(ws + 80740352);
        __bf16* hws  = (__bf16*)(ws + 20185088);
        __bf16* ffn  = xn;
        int*    top_i = (int*)(ws + 100925440);
        float*  gates = (float*)(ws + 100925440 + 1024);

        ln_kernel<<<NTOK, 256, 0, stream>>>(src, ln1_w, ln1_b, xn);
        gemm_k<0, 0, false><<<dim3(24, 77), 256, 0, stream>>>(
            xn, packed_w, packed_b, nullptr, qkv, 3072, 1024,
            nullptr, nullptr, 0, 0, 0);
        attn_mfma<<<dim3(16, 128), 256, 0, stream>>>(qkv, ao);
        gemm_k<0, 2, false><<<dim3(8, 77), 256, 0, stream>>>(
            ao, out_w, out_b, src, out, 1024, 1024,
            nullptr, nullptr, 0, 0, 0);
        ln_kernel<<<NTOK, 256, 0, stream>>>(out, ln2_w, ln2_b, ffn);
        router_kernel<<<128, 256, 0, stream>>>(out, ln2_w, ln2_b, router_w, top_i, gates);
        for (int pass = 0; pass < 2; ++pass) {
            gemm_k<1, 1, true><<<dim3(32, 128), 256, 0, stream>>>(
                ffn, ew1, eb1, nullptr, hws, 4096, 1024,
                top_i, gates, pass, (size_t)1024 * 4096, 4096);
            gemm_k<1, 3, true><<<dim3(8, 128), 256, 0, stream>>>(
                hws, ew2, eb2, nullptr, out, 1024, 4096,
                top_i, gates, pass, (size_t)4096 * 1024, 1024);
        }
        gemm_k<1, 1, false><<<dim3(32, 77), 256, 0, stream>>>(
            ffn, sw1, sb1, nullptr, hws, 4096, 1024,
            nullptr, nullptr, 0, 0, 0);
        gemm_k<1, 3, false><<<dim3(8, 77), 256, 0, stream>>>(
            hws, sw2, sb2, nullptr, out, 1024, 4096,
            nullptr, nullptr, 0, 0, 0);
    }
}